// Round 7
// baseline (58.934 us; speedup 1.0000x reference)
//
#include <hip/hip_runtime.h>

#define NB 32
#define NN 2048
#define NC 16
#define ND 128
#define NH 128
#define NK 384
#define TM 32
#define NBLK (NB * (NN / TM))   // 2048 blocks of 256 threads

typedef __bf16 bf16x8 __attribute__((ext_vector_type(8)));
typedef float f32x4 __attribute__((ext_vector_type(4)));
typedef float f32x2 __attribute__((ext_vector_type(2)));

__device__ __forceinline__ unsigned short f2bf(float f){
  unsigned u = __float_as_uint(f);
  u = (u + 0x7fffu + ((u >> 16) & 1u)) >> 16;   // RNE
  return (unsigned short)u;
}
__device__ __forceinline__ unsigned enc_f32(float x){
  unsigned u = __float_as_uint(x);
  return (u & 0x80000000u) ? ~u : (u | 0x80000000u);
}
__device__ __forceinline__ float dec_f32(unsigned u){
  return __uint_as_float((u & 0x80000000u) ? (u & 0x7fffffffu) : ~u);
}

// swizzled LDS tile helpers (XOR bank swizzle: byte ^= (row&7)<<4)
__device__ __forceinline__ void stq(unsigned char* base, int stride, int row, int koff, uint4 u){
  *(uint4*)(base + row * stride + (koff ^ ((row & 7) << 4))) = u;
}
__device__ __forceinline__ void st8(unsigned char* base, int stride, int row, int koff, const float* f){
  uint4 u;
  u.x = (unsigned)f2bf(f[0]) | ((unsigned)f2bf(f[1]) << 16);
  u.y = (unsigned)f2bf(f[2]) | ((unsigned)f2bf(f[3]) << 16);
  u.z = (unsigned)f2bf(f[4]) | ((unsigned)f2bf(f[5]) << 16);
  u.w = (unsigned)f2bf(f[6]) | ((unsigned)f2bf(f[7]) << 16);
  stq(base, stride, row, koff, u);
}
// pack 4 f32x2 pairs (8 floats) -> 16B bf16 store
__device__ __forceinline__ void st8p(unsigned char* base, int stride, int row, int koff, const f32x2* p){
  uint4 u;
  u.x = (unsigned)f2bf(p[0][0]) | ((unsigned)f2bf(p[0][1]) << 16);
  u.y = (unsigned)f2bf(p[1][0]) | ((unsigned)f2bf(p[1][1]) << 16);
  u.z = (unsigned)f2bf(p[2][0]) | ((unsigned)f2bf(p[2][1]) << 16);
  u.w = (unsigned)f2bf(p[3][0]) | ((unsigned)f2bf(p[3][1]) << 16);
  stq(base, stride, row, koff, u);
}
__device__ __forceinline__ uint4 ldq(const unsigned char* base, int stride, int row, int koff){
  return *(const uint4*)(base + row * stride + (koff ^ ((row & 7) << 4)));
}

// ws layout
#define OFF_POOLED 0
#define OFF_W1     16384
#define OFF_W2     114688
#define OFF_DONE   147456
#define OFF_EMB    147712
#define WS_NEED_BF (OFF_EMB + (size_t)NB*NN*ND*2)

// ---- unified prep ----
__global__ __launch_bounds__(256) void tbcnn_prep(
    const float* __restrict__ nodeEmb, const float* __restrict__ W1,
    const float* __restrict__ W2, unsigned* __restrict__ pooled,
    uint4* __restrict__ w1frag, uint4* __restrict__ w2frag,
    ushort* __restrict__ embBf, unsigned* __restrict__ done, int doEmb)
{
  const int blk = blockIdx.x;
  const int t = threadIdx.x;
  if (blk < 2048){
    if (!doEmb) return;
    // chunk chk covers float4 [chk*1024, chk*1024+1024) -> batch chk>>6 on XCD blk&7
    const int chk = ((blk & 7) << 8) | (blk >> 3);
    const float4* src = (const float4*)nodeEmb;
    #pragma unroll
    for (int it = 0; it < 4; ++it){
      const int i = chk * 1024 + it * 256 + t;
      float4 v = src[i];
      ushort4 o;
      o.x = f2bf(v.x); o.y = f2bf(v.y); o.z = f2bf(v.z); o.w = f2bf(v.w);
      *(ushort4*)(embBf + (size_t)i * 4) = o;
    }
  } else if (blk < 2072){
    const int tt = (blk - 2048) * 256 + t;        // 0..6143
    if (tt < NB * NH) pooled[tt] = 0u;            // enc-min
    if (tt == NB * NH) *done = 0u;
    const int lane = tt & 63;
    const int rest = tt >> 6;                     // 0..95
    const int ks = rest % 12;
    const int cf = rest / 12;
    const int col = (cf >> 1) * 32 + (cf & 1) * 16 + (lane & 15);
    const int k0 = ks * 32 + (lane >> 4) * 8;
    unsigned ps[4];
    #pragma unroll
    for (int p = 0; p < 4; ++p){
      unsigned lo = f2bf(W1[(size_t)(k0 + 2*p) * NH + col]);
      unsigned hi = f2bf(W1[(size_t)(k0 + 2*p + 1) * NH + col]);
      ps[p] = lo | (hi << 16);
    }
    w1frag[tt] = make_uint4(ps[0], ps[1], ps[2], ps[3]);
  } else {
    const int tt = (blk - 2072) * 256 + t;        // 0..2047
    const int lane = tt & 63;
    const int rest = tt >> 6;                     // 0..31
    const int ks = rest & 3;
    const int cf = rest >> 2;
    const int col = (cf >> 1) * 32 + (cf & 1) * 16 + (lane & 15);
    const int k0 = ks * 32 + (lane >> 4) * 8;
    unsigned ps[4];
    #pragma unroll
    for (int p = 0; p < 4; ++p){
      unsigned lo = f2bf(W2[(size_t)(k0 + 2*p) * NH + col]);
      unsigned hi = f2bf(W2[(size_t)(k0 + 2*p + 1) * NH + col]);
      ps[p] = lo | (hi << 16);
    }
    w2frag[tt] = make_uint4(ps[0], ps[1], ps[2], ps[3]);
  }
}

// unpack one uint (2 bf16) and accumulate into f32x2 pairs with packed FMA
#define PROC2(u, p) { \
  f32x2 x_; \
  x_[0] = __uint_as_float((u) << 16); \
  x_[1] = __uint_as_float((u) & 0xffff0000u); \
  aR2[(p)] += w_r * x_; \
  aL2[(p)] += w_l * x_; }

// ---- main: gather + wf (LDS) + MFMA + row-max + atomicMax + fused final ----
// (256,2): 128-VGPR cap (caps below ~64 VGPR spill 300MB — R2/R4). No
// __threadfence in ticket (R5: device fence demoted L2 gather set).
template<bool BF>
__global__ __launch_bounds__(256, 2) void tbcnn_main(
    const int* __restrict__ children, const float* __restrict__ nodeEmb,
    const ushort* __restrict__ embBf, const uint4* __restrict__ w1frag,
    const uint4* __restrict__ w2frag, const float* __restrict__ b1,
    const float* __restrict__ b2, unsigned* __restrict__ pooled,
    unsigned* __restrict__ done, float* __restrict__ out)
{
  __shared__ __align__(16) unsigned char wf_raw[TM * 768];   // 24 KB
  __shared__ unsigned last_flag;
  // XCD-aware swizzle: 2048 blocks = 8 XCDs x 256; each XCD owns 4 batches
  const int j0 = ((blockIdx.x & 7) << 8) | (blockIdx.x >> 3);
  const int b    = j0 >> 6;
  const int n0 = (j0 & 63) * TM;
  const int t = threadIdx.x;
  const int lane = t & 63;
  const int w = t >> 6;

  // ---- gather phase: 8 threads per node, 16 dims each ----
  {
    const int nloc = t >> 3;
    const int q = t & 7;
    const int d0 = q * 16;
    const int gn = n0 + nloc;
    const int4* chp4 = (const int4*)(children + ((size_t)b * NN + gn) * NC);

    int ns = 0;
    #pragma unroll
    for (int c4 = 0; c4 < 4; ++c4){
      int4 v = chp4[c4];
      ns += (v.x > 0) + (v.y > 0) + (v.z > 0) + (v.w > 0);
    }
    const float rdiv = 1.0f / (float)(((ns - 1) > 1) ? (ns - 1) : 1);
    const bool one_sib = (ns == 1);
    const size_t rowbase = (size_t)b * NN;

    // self -> k-block 0
    if (BF){
      const ushort* sp = embBf + (rowbase + gn) * ND + d0;
      stq(wf_raw, 768, nloc, 2 * d0,       *(const uint4*)sp);
      stq(wf_raw, 768, nloc, 2 * (d0 + 8), *(const uint4*)(sp + 8));
    } else {
      const float* sp = nodeEmb + (rowbase + gn) * ND + d0;
      float sv[16];
      #pragma unroll
      for (int j = 0; j < 4; ++j){
        float4 s = *(const float4*)(sp + j * 4);
        sv[j*4+0]=s.x; sv[j*4+1]=s.y; sv[j*4+2]=s.z; sv[j*4+3]=s.w;
      }
      st8(wf_raw, 768, nloc, 2 * d0, sv);
      st8(wf_raw, 768, nloc, 2 * (d0 + 8), sv + 8);
    }

    // children weighted sums: stage 4 children's loads (8 uint4 in flight),
    // then packed-FMA accumulate (v_pk_fma_f32 via f32x2 + ffp-contract)
    f32x2 aR2[8], aL2[8];
    #pragma unroll
    for (int i = 0; i < 8; ++i){ aR2[i] = (f32x2){0.f,0.f}; aL2[i] = (f32x2){0.f,0.f}; }
    #pragma unroll
    for (int c4 = 0; c4 < 4; ++c4){
      int4 v = chp4[c4];
      int cidx[4] = {v.x, v.y, v.z, v.w};
      uint4 u0[4], u1[4];
      #pragma unroll
      for (int jj = 0; jj < 4; ++jj){
        const ushort* cp = embBf + (rowbase + cidx[jj]) * ND + d0;  // idx==0 -> weight 0
        u0[jj] = *(const uint4*)cp;
        u1[jj] = *(const uint4*)(cp + 8);
      }
      #pragma unroll
      for (int jj = 0; jj < 4; ++jj){
        const int c = c4 * 4 + jj;
        const float mk  = (cidx[jj] > 0) ? 1.0f : 0.0f;
        const float wrc = one_sib ? (0.5f * mk) : (mk * (float)c * rdiv);
        const float wlc = (1.0f - wrc) * mk;
        const f32x2 w_r = (f32x2){wrc, wrc};
        const f32x2 w_l = (f32x2){wlc, wlc};
        PROC2(u0[jj].x, 0) PROC2(u0[jj].y, 1) PROC2(u0[jj].z, 2) PROC2(u0[jj].w, 3)
        PROC2(u1[jj].x, 4) PROC2(u1[jj].y, 5) PROC2(u1[jj].z, 6) PROC2(u1[jj].w, 7)
      }
    }
    st8p(wf_raw, 768, nloc, 2 * (ND + d0),         aR2);
    st8p(wf_raw, 768, nloc, 2 * (ND + d0 + 8),     aR2 + 4);
    st8p(wf_raw, 768, nloc, 2 * (2 * ND + d0),     aL2);
    st8p(wf_raw, 768, nloc, 2 * (2 * ND + d0 + 8), aL2 + 4);
  }
  __syncthreads();

  // ---- MFMA: 32 rows x 32 cols per wave, K=384; B frags streamed (L2-hot) ----
  {
    f32x4 acc[2][2];
    #pragma unroll
    for (int rf = 0; rf < 2; ++rf){
      acc[rf][0] = (f32x4){0.f, 0.f, 0.f, 0.f};
      acc[rf][1] = (f32x4){0.f, 0.f, 0.f, 0.f};
    }
    #pragma unroll 4
    for (int ks = 0; ks < 12; ++ks){
      bf16x8 B0 = __builtin_bit_cast(bf16x8, w1frag[((w * 2 + 0) * 12 + ks) * 64 + lane]);
      bf16x8 B1 = __builtin_bit_cast(bf16x8, w1frag[((w * 2 + 1) * 12 + ks) * 64 + lane]);
      const int koff = ks * 64 + ((lane >> 4) << 4);
      #pragma unroll
      for (int rf = 0; rf < 2; ++rf){
        const int row = rf * 16 + (lane & 15);
        bf16x8 a = __builtin_bit_cast(bf16x8, ldq(wf_raw, 768, row, koff));
        acc[rf][0] = __builtin_amdgcn_mfma_f32_16x16x32_bf16(a, B0, acc[rf][0], 0, 0, 0);
        acc[rf][1] = __builtin_amdgcn_mfma_f32_16x16x32_bf16(a, B1, acc[rf][1], 0, 0, 0);
      }
    }

    float m0 = -3.0e38f, m1 = -3.0e38f;
    #pragma unroll
    for (int rf = 0; rf < 2; ++rf)
      #pragma unroll
      for (int i = 0; i < 4; ++i){
        m0 = fmaxf(m0, acc[rf][0][i]);
        m1 = fmaxf(m1, acc[rf][1][i]);
      }
    m0 = fmaxf(m0, __shfl_xor(m0, 16, 64));
    m0 = fmaxf(m0, __shfl_xor(m0, 32, 64));
    m1 = fmaxf(m1, __shfl_xor(m1, 16, 64));
    m1 = fmaxf(m1, __shfl_xor(m1, 32, 64));
    if (lane < 16){
      atomicMax(pooled + b * NH + w * 32 + lane,      enc_f32(m0));
      atomicMax(pooled + b * NH + w * 32 + 16 + lane, enc_f32(m1));
    }
  }

  // ---- last-block ticket (no fence; atomics are device-coherent) ----
  __syncthreads();
  if (t == 0){
    unsigned r = atomicAdd(done, 1u);
    last_flag = (r == NBLK - 1) ? 1u : 0u;
  }
  __syncthreads();
  if (!last_flag) return;

  // ---- fused final (last block only) ----
  unsigned char* hls = wf_raw;                 // 32 x 128 bf16, swizzled, 8 KB
  float* os = (float*)(wf_raw + 8192);         // 32 x 128 f32, 16 KB
  {
    const int row = t >> 3;          // batch
    const int q = t & 7;
    const int d0 = q * 16;
    unsigned* pp = pooled + row * NH + d0;
    const float* bp = b1 + d0;
    float hv[16];
    #pragma unroll
    for (int j = 0; j < 16; ++j) hv[j] = tanhf(dec_f32(atomicMax(pp + j, 0u)) + bp[j]);
    st8(hls, 256, row, 2 * d0, hv);
    st8(hls, 256, row, 2 * (d0 + 8), hv + 8);
  }
  __syncthreads();
  {
    f32x4 acc[2][2];
    #pragma unroll
    for (int rf = 0; rf < 2; ++rf){
      acc[rf][0] = (f32x4){0.f,0.f,0.f,0.f};
      acc[rf][1] = (f32x4){0.f,0.f,0.f,0.f};
    }
    #pragma unroll
    for (int ks = 0; ks < 4; ++ks){
      bf16x8 B0 = __builtin_bit_cast(bf16x8, w2frag[((w * 2 + 0) * 4 + ks) * 64 + lane]);
      bf16x8 B1 = __builtin_bit_cast(bf16x8, w2frag[((w * 2 + 1) * 4 + ks) * 64 + lane]);
      const int koff = ks * 64 + ((lane >> 4) << 4);
      #pragma unroll
      for (int rf = 0; rf < 2; ++rf){
        bf16x8 a = __builtin_bit_cast(bf16x8, ldq(hls, 256, rf * 16 + (lane & 15), koff));
        acc[rf][0] = __builtin_amdgcn_mfma_f32_16x16x32_bf16(a, B0, acc[rf][0], 0, 0, 0);
        acc[rf][1] = __builtin_amdgcn_mfma_f32_16x16x32_bf16(a, B1, acc[rf][1], 0, 0, 0);
      }
    }
    #pragma unroll
    for (int rf = 0; rf < 2; ++rf)
      #pragma unroll
      for (int cf = 0; cf < 2; ++cf){
        const int col = w * 32 + cf * 16 + (lane & 15);
        const float bias = b2[col];
        #pragma unroll
        for (int i = 0; i < 4; ++i){
          const int r = rf * 16 + (lane >> 4) * 4 + i;
          os[r * NH + col] = tanhf(acc[rf][cf][i] + bias);
        }
      }
  }
  __syncthreads();
  if (t < 16){
    float s12 = 0.f, s11 = 0.f, s22 = 0.f;
    #pragma unroll 4
    for (int d = 0; d < NH; ++d){
      float a = os[t * NH + d];
      float c = os[(t + 16) * NH + d];
      s12 += a * c; s11 += a * a; s22 += c * c;
    }
    float n1 = fmaxf(sqrtf(s11), 1e-8f);
    float n2 = fmaxf(sqrtf(s22), 1e-8f);
    out[t] = s12 / (n1 * n2);
  }
}

extern "C" void kernel_launch(void* const* d_in, const int* in_sizes, int n_in,
                              void* d_out, int out_size, void* d_ws, size_t ws_size,
                              hipStream_t stream)
{
  const int*   children = (const int*)d_in[0];
  const float* nodeEmb  = (const float*)d_in[1];
  const float* W1       = (const float*)d_in[2];
  const float* b1       = (const float*)d_in[3];
  const float* W2       = (const float*)d_in[4];
  const float* b2       = (const float*)d_in[5];
  float* out = (float*)d_out;

  unsigned* pooled = (unsigned*)((char*)d_ws + OFF_POOLED);
  uint4* w1frag    = (uint4*)((char*)d_ws + OFF_W1);
  uint4* w2frag    = (uint4*)((char*)d_ws + OFF_W2);
  unsigned* done   = (unsigned*)((char*)d_ws + OFF_DONE);
  ushort* embBf    = (ushort*)((char*)d_ws + OFF_EMB);

  const bool bf = (ws_size >= WS_NEED_BF);

  tbcnn_prep<<<2080, 256, 0, stream>>>(nodeEmb, W1, W2, pooled, w1frag, w2frag, embBf, done, bf ? 1 : 0);
  if (bf)
    tbcnn_main<true><<<NBLK, 256, 0, stream>>>(children, nodeEmb, embBf, w1frag, w2frag, b1, b2, pooled, done, out);
  else
    tbcnn_main<false><<<NBLK, 256, 0, stream>>>(children, nodeEmb, embBf, w1frag, w2frag, b1, b2, pooled, done, out);
}

// Round 8
// 56.096 us; speedup vs baseline: 1.0506x; 1.0506x over previous
//
#include <hip/hip_runtime.h>

#define NB 32
#define NN 2048
#define NC 16
#define ND 128
#define NH 128
#define NK 384
#define TM 32
#define NBLK (NB * (NN / TM))   // 2048 blocks of 256 threads

typedef __bf16 bf16x8 __attribute__((ext_vector_type(8)));
typedef float f32x4 __attribute__((ext_vector_type(4)));
typedef float f32x2 __attribute__((ext_vector_type(2)));

__device__ __forceinline__ unsigned short f2bf(float f){
  unsigned u = __float_as_uint(f);
  u = (u + 0x7fffu + ((u >> 16) & 1u)) >> 16;   // RNE
  return (unsigned short)u;
}
__device__ __forceinline__ unsigned enc_f32(float x){
  unsigned u = __float_as_uint(x);
  return (u & 0x80000000u) ? ~u : (u | 0x80000000u);
}
__device__ __forceinline__ float dec_f32(unsigned u){
  return __uint_as_float((u & 0x80000000u) ? (u & 0x7fffffffu) : ~u);
}

// swizzled LDS tile helpers (XOR bank swizzle: byte ^= (row&7)<<4)
__device__ __forceinline__ void stq(unsigned char* base, int stride, int row, int koff, uint4 u){
  *(uint4*)(base + row * stride + (koff ^ ((row & 7) << 4))) = u;
}
__device__ __forceinline__ void st8(unsigned char* base, int stride, int row, int koff, const float* f){
  uint4 u;
  u.x = (unsigned)f2bf(f[0]) | ((unsigned)f2bf(f[1]) << 16);
  u.y = (unsigned)f2bf(f[2]) | ((unsigned)f2bf(f[3]) << 16);
  u.z = (unsigned)f2bf(f[4]) | ((unsigned)f2bf(f[5]) << 16);
  u.w = (unsigned)f2bf(f[6]) | ((unsigned)f2bf(f[7]) << 16);
  stq(base, stride, row, koff, u);
}
// pack 4 f32x2 pairs (8 floats) -> 16B bf16 store
__device__ __forceinline__ void st8p(unsigned char* base, int stride, int row, int koff, const f32x2* p){
  uint4 u;
  u.x = (unsigned)f2bf(p[0][0]) | ((unsigned)f2bf(p[0][1]) << 16);
  u.y = (unsigned)f2bf(p[1][0]) | ((unsigned)f2bf(p[1][1]) << 16);
  u.z = (unsigned)f2bf(p[2][0]) | ((unsigned)f2bf(p[2][1]) << 16);
  u.w = (unsigned)f2bf(p[3][0]) | ((unsigned)f2bf(p[3][1]) << 16);
  stq(base, stride, row, koff, u);
}
__device__ __forceinline__ uint4 ldq(const unsigned char* base, int stride, int row, int koff){
  return *(const uint4*)(base + row * stride + (koff ^ ((row & 7) << 4)));
}

// ws layout
#define OFF_POOLED 0
#define OFF_W1     16384
#define OFF_W2     114688
#define OFF_DONE   147456
#define OFF_EMB    147712
#define WS_NEED_BF (OFF_EMB + (size_t)NB*NN*ND*2)

// ---- unified prep ----
__global__ __launch_bounds__(256) void tbcnn_prep(
    const float* __restrict__ nodeEmb, const float* __restrict__ W1,
    const float* __restrict__ W2, unsigned* __restrict__ pooled,
    uint4* __restrict__ w1frag, uint4* __restrict__ w2frag,
    ushort* __restrict__ embBf, unsigned* __restrict__ done, int doEmb)
{
  const int blk = blockIdx.x;
  const int t = threadIdx.x;
  if (blk < 2048){
    if (!doEmb) return;
    // chunk chk covers float4 [chk*1024, chk*1024+1024) -> batch chk>>6 on XCD blk&7
    const int chk = ((blk & 7) << 8) | (blk >> 3);
    const float4* src = (const float4*)nodeEmb;
    #pragma unroll
    for (int it = 0; it < 4; ++it){
      const int i = chk * 1024 + it * 256 + t;
      float4 v = src[i];
      ushort4 o;
      o.x = f2bf(v.x); o.y = f2bf(v.y); o.z = f2bf(v.z); o.w = f2bf(v.w);
      *(ushort4*)(embBf + (size_t)i * 4) = o;
    }
  } else if (blk < 2072){
    const int tt = (blk - 2048) * 256 + t;        // 0..6143
    if (tt < NB * NH) pooled[tt] = 0u;            // enc-min
    if (tt == NB * NH) *done = 0u;
    const int lane = tt & 63;
    const int rest = tt >> 6;                     // 0..95
    const int ks = rest % 12;
    const int cf = rest / 12;
    const int col = (cf >> 1) * 32 + (cf & 1) * 16 + (lane & 15);
    const int k0 = ks * 32 + (lane >> 4) * 8;
    unsigned ps[4];
    #pragma unroll
    for (int p = 0; p < 4; ++p){
      unsigned lo = f2bf(W1[(size_t)(k0 + 2*p) * NH + col]);
      unsigned hi = f2bf(W1[(size_t)(k0 + 2*p + 1) * NH + col]);
      ps[p] = lo | (hi << 16);
    }
    w1frag[tt] = make_uint4(ps[0], ps[1], ps[2], ps[3]);
  } else {
    const int tt = (blk - 2072) * 256 + t;        // 0..2047
    const int lane = tt & 63;
    const int rest = tt >> 6;                     // 0..31
    const int ks = rest & 3;
    const int cf = rest >> 2;
    const int col = (cf >> 1) * 32 + (cf & 1) * 16 + (lane & 15);
    const int k0 = ks * 32 + (lane >> 4) * 8;
    unsigned ps[4];
    #pragma unroll
    for (int p = 0; p < 4; ++p){
      unsigned lo = f2bf(W2[(size_t)(k0 + 2*p) * NH + col]);
      unsigned hi = f2bf(W2[(size_t)(k0 + 2*p + 1) * NH + col]);
      ps[p] = lo | (hi << 16);
    }
    w2frag[tt] = make_uint4(ps[0], ps[1], ps[2], ps[3]);
  }
}

// unpack one uint (2 bf16) and accumulate into f32x2 pairs with packed FMA
#define PROC2(u, p) { \
  f32x2 x_; \
  x_[0] = __uint_as_float((u) << 16); \
  x_[1] = __uint_as_float((u) & 0xffff0000u); \
  aR2[(p)] += w_r * x_; \
  aL2[(p)] += w_l * x_; }

// issue 4 children's low-half (dims d0..d0+7) 16B loads
#define ISSUE_LO(vv, D) { \
  D[0] = *(const uint4*)(embBf + (rowbase + (vv).x) * ND + d0); \
  D[1] = *(const uint4*)(embBf + (rowbase + (vv).y) * ND + d0); \
  D[2] = *(const uint4*)(embBf + (rowbase + (vv).z) * ND + d0); \
  D[3] = *(const uint4*)(embBf + (rowbase + (vv).w) * ND + d0); }
// issue 4 children's high-half (dims d0+8..d0+15)
#define ISSUE_HI(vv, D) { \
  D[0] = *(const uint4*)(embBf + (rowbase + (vv).x) * ND + d0 + 8); \
  D[1] = *(const uint4*)(embBf + (rowbase + (vv).y) * ND + d0 + 8); \
  D[2] = *(const uint4*)(embBf + (rowbase + (vv).z) * ND + d0 + 8); \
  D[3] = *(const uint4*)(embBf + (rowbase + (vv).w) * ND + d0 + 8); }

#define CW(c, idx) \
  const float mk  = ((idx) > 0) ? 1.0f : 0.0f; \
  const float wrc = one_sib ? (0.5f * mk) : (mk * (float)(c) * rdiv); \
  const float wlc = (1.0f - wrc) * mk; \
  const f32x2 w_r = (f32x2){wrc, wrc}; \
  const f32x2 w_l = (f32x2){wlc, wlc};

// process low halves of 4 children (group g): pairs 0..3
#define PROC_LO(g, vv, U) { \
  { CW(4*(g)+0, (vv).x) PROC2(U[0].x, 0) PROC2(U[0].y, 1) PROC2(U[0].z, 2) PROC2(U[0].w, 3) } \
  { CW(4*(g)+1, (vv).y) PROC2(U[1].x, 0) PROC2(U[1].y, 1) PROC2(U[1].z, 2) PROC2(U[1].w, 3) } \
  { CW(4*(g)+2, (vv).z) PROC2(U[2].x, 0) PROC2(U[2].y, 1) PROC2(U[2].z, 2) PROC2(U[2].w, 3) } \
  { CW(4*(g)+3, (vv).w) PROC2(U[3].x, 0) PROC2(U[3].y, 1) PROC2(U[3].z, 2) PROC2(U[3].w, 3) } }
// process high halves: pairs 4..7
#define PROC_HI(g, vv, U) { \
  { CW(4*(g)+0, (vv).x) PROC2(U[0].x, 4) PROC2(U[0].y, 5) PROC2(U[0].z, 6) PROC2(U[0].w, 7) } \
  { CW(4*(g)+1, (vv).y) PROC2(U[1].x, 4) PROC2(U[1].y, 5) PROC2(U[1].z, 6) PROC2(U[1].w, 7) } \
  { CW(4*(g)+2, (vv).z) PROC2(U[2].x, 4) PROC2(U[2].y, 5) PROC2(U[2].z, 6) PROC2(U[2].w, 7) } \
  { CW(4*(g)+3, (vv).w) PROC2(U[3].x, 4) PROC2(U[3].y, 5) PROC2(U[3].z, 6) PROC2(U[3].w, 7) } }

// ---- main: gather + wf (LDS) + MFMA + row-max + atomicMax + fused final ----
// (256,2): 128-VGPR cap (caps below ~64 VGPR spill 300MB — R2/R4). No
// __threadfence in ticket (R5: device fence demoted L2 gather set).
// Gather is software-pipelined with sched_barrier(0) fences: R7 showed the
// compiler re-serializes staged loads (VGPR 80->44) unless fenced.
template<bool BF>
__global__ __launch_bounds__(256, 2) void tbcnn_main(
    const int* __restrict__ children, const float* __restrict__ nodeEmb,
    const ushort* __restrict__ embBf, const uint4* __restrict__ w1frag,
    const uint4* __restrict__ w2frag, const float* __restrict__ b1,
    const float* __restrict__ b2, unsigned* __restrict__ pooled,
    unsigned* __restrict__ done, float* __restrict__ out)
{
  __shared__ __align__(16) unsigned char wf_raw[TM * 768];   // 24 KB
  __shared__ unsigned last_flag;
  // XCD-aware swizzle: 2048 blocks = 8 XCDs x 256; each XCD owns 4 batches
  const int j0 = ((blockIdx.x & 7) << 8) | (blockIdx.x >> 3);
  const int b    = j0 >> 6;
  const int n0 = (j0 & 63) * TM;
  const int t = threadIdx.x;
  const int lane = t & 63;
  const int w = t >> 6;

  // ---- gather phase: 8 threads per node, 16 dims each ----
  {
    const int nloc = t >> 3;
    const int q = t & 7;
    const int d0 = q * 16;
    const int gn = n0 + nloc;
    const int4* chp4 = (const int4*)(children + ((size_t)b * NN + gn) * NC);
    const size_t rowbase = (size_t)b * NN;

    const int4 vA = chp4[0], vB = chp4[1], vC = chp4[2], vD = chp4[3];
    int ns = (vA.x > 0) + (vA.y > 0) + (vA.z > 0) + (vA.w > 0)
           + (vB.x > 0) + (vB.y > 0) + (vB.z > 0) + (vB.w > 0)
           + (vC.x > 0) + (vC.y > 0) + (vC.z > 0) + (vC.w > 0)
           + (vD.x > 0) + (vD.y > 0) + (vD.z > 0) + (vD.w > 0);
    const float rdiv = 1.0f / (float)(((ns - 1) > 1) ? (ns - 1) : 1);
    const bool one_sib = (ns == 1);

    // self -> k-block 0
    {
      const ushort* sp = embBf + (rowbase + gn) * ND + d0;
      stq(wf_raw, 768, nloc, 2 * d0,       *(const uint4*)sp);
      stq(wf_raw, 768, nloc, 2 * (d0 + 8), *(const uint4*)(sp + 8));
    }

    // children weighted sums, software-pipelined:
    // round g: issue {hi of g, lo of g+1} (8 loads in flight), fence, process g.
    f32x2 aR2[8], aL2[8];
    #pragma unroll
    for (int i = 0; i < 8; ++i){ aR2[i] = (f32x2){0.f,0.f}; aL2[i] = (f32x2){0.f,0.f}; }

    uint4 s0[4], t0[4], s1[4];           // named buffers, static indexing only
    ISSUE_LO(vA, s0)
    // round 0 (group A in s0)
    ISSUE_HI(vA, s1)
    ISSUE_LO(vB, t0)
    __builtin_amdgcn_sched_barrier(0);
    PROC_LO(0, vA, s0)
    PROC_HI(0, vA, s1)
    // round 1 (group B in t0)
    ISSUE_HI(vB, s1)
    ISSUE_LO(vC, s0)
    __builtin_amdgcn_sched_barrier(0);
    PROC_LO(1, vB, t0)
    PROC_HI(1, vB, s1)
    // round 2 (group C in s0)
    ISSUE_HI(vC, s1)
    ISSUE_LO(vD, t0)
    __builtin_amdgcn_sched_barrier(0);
    PROC_LO(2, vC, s0)
    PROC_HI(2, vC, s1)
    // round 3 (group D in t0)
    ISSUE_HI(vD, s1)
    __builtin_amdgcn_sched_barrier(0);
    PROC_LO(3, vD, t0)
    PROC_HI(3, vD, s1)

    st8p(wf_raw, 768, nloc, 2 * (ND + d0),         aR2);
    st8p(wf_raw, 768, nloc, 2 * (ND + d0 + 8),     aR2 + 4);
    st8p(wf_raw, 768, nloc, 2 * (2 * ND + d0),     aL2);
    st8p(wf_raw, 768, nloc, 2 * (2 * ND + d0 + 8), aL2 + 4);
  }
  __syncthreads();

  // ---- MFMA: 32 rows x 32 cols per wave, K=384; B frags streamed (L2-hot) ----
  {
    f32x4 acc[2][2];
    #pragma unroll
    for (int rf = 0; rf < 2; ++rf){
      acc[rf][0] = (f32x4){0.f, 0.f, 0.f, 0.f};
      acc[rf][1] = (f32x4){0.f, 0.f, 0.f, 0.f};
    }
    #pragma unroll 4
    for (int ks = 0; ks < 12; ++ks){
      bf16x8 B0 = __builtin_bit_cast(bf16x8, w1frag[((w * 2 + 0) * 12 + ks) * 64 + lane]);
      bf16x8 B1 = __builtin_bit_cast(bf16x8, w1frag[((w * 2 + 1) * 12 + ks) * 64 + lane]);
      const int koff = ks * 64 + ((lane >> 4) << 4);
      #pragma unroll
      for (int rf = 0; rf < 2; ++rf){
        const int row = rf * 16 + (lane & 15);
        bf16x8 a = __builtin_bit_cast(bf16x8, ldq(wf_raw, 768, row, koff));
        acc[rf][0] = __builtin_amdgcn_mfma_f32_16x16x32_bf16(a, B0, acc[rf][0], 0, 0, 0);
        acc[rf][1] = __builtin_amdgcn_mfma_f32_16x16x32_bf16(a, B1, acc[rf][1], 0, 0, 0);
      }
    }

    float m0 = -3.0e38f, m1 = -3.0e38f;
    #pragma unroll
    for (int rf = 0; rf < 2; ++rf)
      #pragma unroll
      for (int i = 0; i < 4; ++i){
        m0 = fmaxf(m0, acc[rf][0][i]);
        m1 = fmaxf(m1, acc[rf][1][i]);
      }
    m0 = fmaxf(m0, __shfl_xor(m0, 16, 64));
    m0 = fmaxf(m0, __shfl_xor(m0, 32, 64));
    m1 = fmaxf(m1, __shfl_xor(m1, 16, 64));
    m1 = fmaxf(m1, __shfl_xor(m1, 32, 64));
    if (lane < 16){
      atomicMax(pooled + b * NH + w * 32 + lane,      enc_f32(m0));
      atomicMax(pooled + b * NH + w * 32 + 16 + lane, enc_f32(m1));
    }
  }

  // ---- last-block ticket (no fence; atomics are device-coherent) ----
  __syncthreads();
  if (t == 0){
    unsigned r = atomicAdd(done, 1u);
    last_flag = (r == NBLK - 1) ? 1u : 0u;
  }
  __syncthreads();
  if (!last_flag) return;

  // ---- fused final (last block only) ----
  unsigned char* hls = wf_raw;                 // 32 x 128 bf16, swizzled, 8 KB
  float* os = (float*)(wf_raw + 8192);         // 32 x 128 f32, 16 KB
  {
    const int row = t >> 3;          // batch
    const int q = t & 7;
    const int d0 = q * 16;
    unsigned* pp = pooled + row * NH + d0;
    const float* bp = b1 + d0;
    float hv[16];
    #pragma unroll
    for (int j = 0; j < 16; ++j) hv[j] = tanhf(dec_f32(atomicMax(pp + j, 0u)) + bp[j]);
    st8(hls, 256, row, 2 * d0, hv);
    st8(hls, 256, row, 2 * (d0 + 8), hv + 8);
  }
  __syncthreads();
  {
    f32x4 acc[2][2];
    #pragma unroll
    for (int rf = 0; rf < 2; ++rf){
      acc[rf][0] = (f32x4){0.f,0.f,0.f,0.f};
      acc[rf][1] = (f32x4){0.f,0.f,0.f,0.f};
    }
    #pragma unroll
    for (int ks = 0; ks < 4; ++ks){
      bf16x8 B0 = __builtin_bit_cast(bf16x8, w2frag[((w * 2 + 0) * 4 + ks) * 64 + lane]);
      bf16x8 B1 = __builtin_bit_cast(bf16x8, w2frag[((w * 2 + 1) * 4 + ks) * 64 + lane]);
      const int koff = ks * 64 + ((lane >> 4) << 4);
      #pragma unroll
      for (int rf = 0; rf < 2; ++rf){
        bf16x8 a = __builtin_bit_cast(bf16x8, ldq(hls, 256, rf * 16 + (lane & 15), koff));
        acc[rf][0] = __builtin_amdgcn_mfma_f32_16x16x32_bf16(a, B0, acc[rf][0], 0, 0, 0);
        acc[rf][1] = __builtin_amdgcn_mfma_f32_16x16x32_bf16(a, B1, acc[rf][1], 0, 0, 0);
      }
    }
    #pragma unroll
    for (int rf = 0; rf < 2; ++rf)
      #pragma unroll
      for (int cf = 0; cf < 2; ++cf){
        const int col = w * 32 + cf * 16 + (lane & 15);
        const float bias = b2[col];
        #pragma unroll
        for (int i = 0; i < 4; ++i){
          const int r = rf * 16 + (lane >> 4) * 4 + i;
          os[r * NH + col] = tanhf(acc[rf][cf][i] + bias);
        }
      }
  }
  __syncthreads();
  if (t < 16){
    float s12 = 0.f, s11 = 0.f, s22 = 0.f;
    #pragma unroll 4
    for (int d = 0; d < NH; ++d){
      float a = os[t * NH + d];
      float c = os[(t + 16) * NH + d];
      s12 += a * c; s11 += a * a; s22 += c * c;
    }
    float n1 = fmaxf(sqrtf(s11), 1e-8f);
    float n2 = fmaxf(sqrtf(s22), 1e-8f);
    out[t] = s12 / (n1 * n2);
  }
}

extern "C" void kernel_launch(void* const* d_in, const int* in_sizes, int n_in,
                              void* d_out, int out_size, void* d_ws, size_t ws_size,
                              hipStream_t stream)
{
  const int*   children = (const int*)d_in[0];
  const float* nodeEmb  = (const float*)d_in[1];
  const float* W1       = (const float*)d_in[2];
  const float* b1       = (const float*)d_in[3];
  const float* W2       = (const float*)d_in[4];
  const float* b2       = (const float*)d_in[5];
  float* out = (float*)d_out;

  unsigned* pooled = (unsigned*)((char*)d_ws + OFF_POOLED);
  uint4* w1frag    = (uint4*)((char*)d_ws + OFF_W1);
  uint4* w2frag    = (uint4*)((char*)d_ws + OFF_W2);
  unsigned* done   = (unsigned*)((char*)d_ws + OFF_DONE);
  ushort* embBf    = (ushort*)((char*)d_ws + OFF_EMB);

  const bool bf = (ws_size >= WS_NEED_BF);

  tbcnn_prep<<<2080, 256, 0, stream>>>(nodeEmb, W1, W2, pooled, w1frag, w2frag, embBf, done, bf ? 1 : 0);
  if (bf)
    tbcnn_main<true><<<NBLK, 256, 0, stream>>>(children, nodeEmb, embBf, w1frag, w2frag, b1, b2, pooled, done, out);
  else
    tbcnn_main<false><<<NBLK, 256, 0, stream>>>(children, nodeEmb, embBf, w1frag, w2frag, b1, b2, pooled, done, out);
}

// Round 9
// 51.962 us; speedup vs baseline: 1.1342x; 1.0796x over previous
//
#include <hip/hip_runtime.h>

#define NB 32
#define NN 2048
#define NC 16
#define ND 128
#define NH 128
#define TM 32
#define TPB 4
#define NBLK2 512               // 512 blocks x 4 tiles; exactly 2 blocks/CU
#define NBLKF 2048              // f32 fallback grid

typedef __bf16 bf16x8 __attribute__((ext_vector_type(8)));
typedef float f32x4 __attribute__((ext_vector_type(4)));
typedef float f32x2 __attribute__((ext_vector_type(2)));

__device__ __forceinline__ unsigned short f2bf(float f){
  unsigned u = __float_as_uint(f);
  u = (u + 0x7fffu + ((u >> 16) & 1u)) >> 16;   // RNE
  return (unsigned short)u;
}
__device__ __forceinline__ unsigned enc_f32(float x){
  unsigned u = __float_as_uint(x);
  return (u & 0x80000000u) ? ~u : (u | 0x80000000u);
}
__device__ __forceinline__ float dec_f32(unsigned u){
  return __uint_as_float((u & 0x80000000u) ? (u & 0x7fffffffu) : ~u);
}

// swizzled LDS tile helpers (XOR bank swizzle: byte ^= (row&7)<<4)
__device__ __forceinline__ void stq(unsigned char* base, int stride, int row, int koff, uint4 u){
  *(uint4*)(base + row * stride + (koff ^ ((row & 7) << 4))) = u;
}
__device__ __forceinline__ void st8(unsigned char* base, int stride, int row, int koff, const float* f){
  uint4 u;
  u.x = (unsigned)f2bf(f[0]) | ((unsigned)f2bf(f[1]) << 16);
  u.y = (unsigned)f2bf(f[2]) | ((unsigned)f2bf(f[3]) << 16);
  u.z = (unsigned)f2bf(f[4]) | ((unsigned)f2bf(f[5]) << 16);
  u.w = (unsigned)f2bf(f[6]) | ((unsigned)f2bf(f[7]) << 16);
  stq(base, stride, row, koff, u);
}
__device__ __forceinline__ void st8p(unsigned char* base, int stride, int row, int koff, const f32x2* p){
  uint4 u;
  u.x = (unsigned)f2bf(p[0][0]) | ((unsigned)f2bf(p[0][1]) << 16);
  u.y = (unsigned)f2bf(p[1][0]) | ((unsigned)f2bf(p[1][1]) << 16);
  u.z = (unsigned)f2bf(p[2][0]) | ((unsigned)f2bf(p[2][1]) << 16);
  u.w = (unsigned)f2bf(p[3][0]) | ((unsigned)f2bf(p[3][1]) << 16);
  stq(base, stride, row, koff, u);
}
__device__ __forceinline__ uint4 ldq(const unsigned char* base, int stride, int row, int koff){
  return *(const uint4*)(base + row * stride + (koff ^ ((row & 7) << 4)));
}

// ws layout
#define OFF_POOLED 0
#define OFF_W1     16384
#define OFF_W2     114688
#define OFF_DONE   147456
#define OFF_EMB    147712
#define WS_NEED_BF (OFF_EMB + (size_t)NB*NN*ND*2)

// ---- unified prep (unchanged) ----
__global__ __launch_bounds__(256) void tbcnn_prep(
    const float* __restrict__ nodeEmb, const float* __restrict__ W1,
    const float* __restrict__ W2, unsigned* __restrict__ pooled,
    uint4* __restrict__ w1frag, uint4* __restrict__ w2frag,
    ushort* __restrict__ embBf, unsigned* __restrict__ done, int doEmb)
{
  const int blk = blockIdx.x;
  const int t = threadIdx.x;
  if (blk < 2048){
    if (!doEmb) return;
    const int chk = ((blk & 7) << 8) | (blk >> 3);
    const float4* src = (const float4*)nodeEmb;
    #pragma unroll
    for (int it = 0; it < 4; ++it){
      const int i = chk * 1024 + it * 256 + t;
      float4 v = src[i];
      ushort4 o;
      o.x = f2bf(v.x); o.y = f2bf(v.y); o.z = f2bf(v.z); o.w = f2bf(v.w);
      *(ushort4*)(embBf + (size_t)i * 4) = o;
    }
  } else if (blk < 2072){
    const int tt = (blk - 2048) * 256 + t;
    if (tt < NB * NH) pooled[tt] = 0u;
    if (tt == NB * NH) *done = 0u;
    const int lane = tt & 63;
    const int rest = tt >> 6;
    const int ks = rest % 12;
    const int cf = rest / 12;
    const int col = (cf >> 1) * 32 + (cf & 1) * 16 + (lane & 15);
    const int k0 = ks * 32 + (lane >> 4) * 8;
    unsigned ps[4];
    #pragma unroll
    for (int p = 0; p < 4; ++p){
      unsigned lo = f2bf(W1[(size_t)(k0 + 2*p) * NH + col]);
      unsigned hi = f2bf(W1[(size_t)(k0 + 2*p + 1) * NH + col]);
      ps[p] = lo | (hi << 16);
    }
    w1frag[tt] = make_uint4(ps[0], ps[1], ps[2], ps[3]);
  } else {
    const int tt = (blk - 2072) * 256 + t;
    const int lane = tt & 63;
    const int rest = tt >> 6;
    const int ks = rest & 3;
    const int cf = rest >> 2;
    const int col = (cf >> 1) * 32 + (cf & 1) * 16 + (lane & 15);
    const int k0 = ks * 32 + (lane >> 4) * 8;
    unsigned ps[4];
    #pragma unroll
    for (int p = 0; p < 4; ++p){
      unsigned lo = f2bf(W2[(size_t)(k0 + 2*p) * NH + col]);
      unsigned hi = f2bf(W2[(size_t)(k0 + 2*p + 1) * NH + col]);
      ps[p] = lo | (hi << 16);
    }
    w2frag[tt] = make_uint4(ps[0], ps[1], ps[2], ps[3]);
  }
}

#define PROC2(u, p) { \
  f32x2 x_; \
  x_[0] = __uint_as_float((u) << 16); \
  x_[1] = __uint_as_float((u) & 0xffff0000u); \
  aR2[(p)] += w_r * x_; \
  aL2[(p)] += w_l * x_; }

#define ISSUE_LO(vv, D) { \
  D[0] = *(const uint4*)(embBf + (rowbase + (vv).x) * ND + d0); \
  D[1] = *(const uint4*)(embBf + (rowbase + (vv).y) * ND + d0); \
  D[2] = *(const uint4*)(embBf + (rowbase + (vv).z) * ND + d0); \
  D[3] = *(const uint4*)(embBf + (rowbase + (vv).w) * ND + d0); }
#define ISSUE_HI(vv, D) { \
  D[0] = *(const uint4*)(embBf + (rowbase + (vv).x) * ND + d0 + 8); \
  D[1] = *(const uint4*)(embBf + (rowbase + (vv).y) * ND + d0 + 8); \
  D[2] = *(const uint4*)(embBf + (rowbase + (vv).z) * ND + d0 + 8); \
  D[3] = *(const uint4*)(embBf + (rowbase + (vv).w) * ND + d0 + 8); }

#define CW(c, idx) \
  const float mk  = ((idx) > 0) ? 1.0f : 0.0f; \
  const float wrc = one_sib ? (0.5f * mk) : (mk * (float)(c) * rdiv); \
  const float wlc = (1.0f - wrc) * mk; \
  const f32x2 w_r = (f32x2){wrc, wrc}; \
  const f32x2 w_l = (f32x2){wlc, wlc};

#define PROC_LO(g, vv, U) { \
  { CW(4*(g)+0, (vv).x) PROC2(U[0].x, 0) PROC2(U[0].y, 1) PROC2(U[0].z, 2) PROC2(U[0].w, 3) } \
  { CW(4*(g)+1, (vv).y) PROC2(U[1].x, 0) PROC2(U[1].y, 1) PROC2(U[1].z, 2) PROC2(U[1].w, 3) } \
  { CW(4*(g)+2, (vv).z) PROC2(U[2].x, 0) PROC2(U[2].y, 1) PROC2(U[2].z, 2) PROC2(U[2].w, 3) } \
  { CW(4*(g)+3, (vv).w) PROC2(U[3].x, 0) PROC2(U[3].y, 1) PROC2(U[3].z, 2) PROC2(U[3].w, 3) } }
#define PROC_HI(g, vv, U) { \
  { CW(4*(g)+0, (vv).x) PROC2(U[0].x, 4) PROC2(U[0].y, 5) PROC2(U[0].z, 6) PROC2(U[0].w, 7) } \
  { CW(4*(g)+1, (vv).y) PROC2(U[1].x, 4) PROC2(U[1].y, 5) PROC2(U[1].z, 6) PROC2(U[1].w, 7) } \
  { CW(4*(g)+2, (vv).z) PROC2(U[2].x, 4) PROC2(U[2].y, 5) PROC2(U[2].z, 6) PROC2(U[2].w, 7) } \
  { CW(4*(g)+3, (vv).w) PROC2(U[3].x, 4) PROC2(U[3].y, 5) PROC2(U[3].z, 6) PROC2(U[3].w, 7) } }

#define MFMA_STEP(KS) { \
  bf16x8 B0_ = __builtin_bit_cast(bf16x8, w1frag[((w * 2 + 0) * 12 + (KS)) * 64 + lane]); \
  bf16x8 B1_ = __builtin_bit_cast(bf16x8, w1frag[((w * 2 + 1) * 12 + (KS)) * 64 + lane]); \
  const int koff_ = (KS) * 64 + ((lane >> 4) << 4); \
  bf16x8 a0_ = __builtin_bit_cast(bf16x8, ldq(bufc, 768, (lane & 15), koff_)); \
  bf16x8 a1_ = __builtin_bit_cast(bf16x8, ldq(bufc, 768, 16 + (lane & 15), koff_)); \
  acc00 = __builtin_amdgcn_mfma_f32_16x16x32_bf16(a0_, B0_, acc00, 0, 0, 0); \
  acc01 = __builtin_amdgcn_mfma_f32_16x16x32_bf16(a0_, B1_, acc01, 0, 0, 0); \
  acc10 = __builtin_amdgcn_mfma_f32_16x16x32_bf16(a1_, B0_, acc10, 0, 0, 0); \
  acc11 = __builtin_amdgcn_mfma_f32_16x16x32_bf16(a1_, B1_, acc11, 0, 0, 0); }

#define EPI_MAXATOMIC { \
  float m0 = fmaxf(fmaxf(fmaxf(acc00[0], acc00[1]), fmaxf(acc00[2], acc00[3])), \
                   fmaxf(fmaxf(acc10[0], acc10[1]), fmaxf(acc10[2], acc10[3]))); \
  float m1 = fmaxf(fmaxf(fmaxf(acc01[0], acc01[1]), fmaxf(acc01[2], acc01[3])), \
                   fmaxf(fmaxf(acc11[0], acc11[1]), fmaxf(acc11[2], acc11[3]))); \
  m0 = fmaxf(m0, __shfl_xor(m0, 16, 64)); m0 = fmaxf(m0, __shfl_xor(m0, 32, 64)); \
  m1 = fmaxf(m1, __shfl_xor(m1, 16, 64)); m1 = fmaxf(m1, __shfl_xor(m1, 32, 64)); \
  if (lane < 16){ \
    atomicMax(pooled + b * NH + w * 32 + lane,      enc_f32(m0)); \
    atomicMax(pooled + b * NH + w * 32 + 16 + lane, enc_f32(m1)); } }

#define STORE_ACC(dst) { \
  st8p(dst, 768, nloc, 2 * (ND + d0),          aR2); \
  st8p(dst, 768, nloc, 2 * (ND + d0 + 8),      aR2 + 4); \
  st8p(dst, 768, nloc, 2 * (2 * ND + d0),      aL2); \
  st8p(dst, 768, nloc, 2 * (2 * ND + d0 + 8),  aL2 + 4); }

// fused final epilogue, shared by both kernels (hls/os overlay a 24KB LDS buf)
#define FUSED_FINAL(HLS_BUF) { \
  unsigned char* hls = (HLS_BUF); \
  float* os = (float*)((HLS_BUF) + 8192); \
  { \
    const int row = t >> 3; \
    const int q2 = t & 7; \
    const int dd = q2 * 16; \
    unsigned* pp = pooled + row * NH + dd; \
    const float* bp = b1 + dd; \
    float hv[16]; \
    _Pragma("unroll") \
    for (int j = 0; j < 16; ++j) hv[j] = tanhf(dec_f32(atomicMax(pp + j, 0u)) + bp[j]); \
    st8(hls, 256, row, 2 * dd, hv); \
    st8(hls, 256, row, 2 * (dd + 8), hv + 8); \
  } \
  __syncthreads(); \
  { \
    f32x4 fa[2][2]; \
    _Pragma("unroll") \
    for (int rf = 0; rf < 2; ++rf){ fa[rf][0] = (f32x4){0.f,0.f,0.f,0.f}; fa[rf][1] = (f32x4){0.f,0.f,0.f,0.f}; } \
    _Pragma("unroll") \
    for (int ks = 0; ks < 4; ++ks){ \
      bf16x8 B0 = __builtin_bit_cast(bf16x8, w2frag[((w * 2 + 0) * 4 + ks) * 64 + lane]); \
      bf16x8 B1 = __builtin_bit_cast(bf16x8, w2frag[((w * 2 + 1) * 4 + ks) * 64 + lane]); \
      const int koff = ks * 64 + ((lane >> 4) << 4); \
      _Pragma("unroll") \
      for (int rf = 0; rf < 2; ++rf){ \
        bf16x8 a = __builtin_bit_cast(bf16x8, ldq(hls, 256, rf * 16 + (lane & 15), koff)); \
        fa[rf][0] = __builtin_amdgcn_mfma_f32_16x16x32_bf16(a, B0, fa[rf][0], 0, 0, 0); \
        fa[rf][1] = __builtin_amdgcn_mfma_f32_16x16x32_bf16(a, B1, fa[rf][1], 0, 0, 0); \
      } \
    } \
    _Pragma("unroll") \
    for (int rf = 0; rf < 2; ++rf) \
      _Pragma("unroll") \
      for (int cf = 0; cf < 2; ++cf){ \
        const int col = w * 32 + cf * 16 + (lane & 15); \
        const float bias = b2[col]; \
        _Pragma("unroll") \
        for (int i = 0; i < 4; ++i){ \
          const int r = rf * 16 + (lane >> 4) * 4 + i; \
          os[r * NH + col] = tanhf(fa[rf][cf][i] + bias); \
        } \
      } \
  } \
  __syncthreads(); \
  if (t < 16){ \
    float s12 = 0.f, s11 = 0.f, s22 = 0.f; \
    _Pragma("unroll 4") \
    for (int d = 0; d < NH; ++d){ \
      float a = os[t * NH + d]; \
      float c = os[(t + 16) * NH + d]; \
      s12 += a * c; s11 += a * a; s22 += c * c; \
    } \
    float n1 = fmaxf(sqrtf(s11), 1e-8f); \
    float n2 = fmaxf(sqrtf(s22), 1e-8f); \
    out[t] = s12 / (n1 * n2); \
  } }

// ---- main (bf16): 512 blocks x 4 tiles, double-buffered LDS, gather(next)
// interleaved with MFMA(cur) via sched_barrier fences. (256,2) = 256-VGPR cap,
// 2 blocks/CU — grid is exactly 2/CU so occupancy is guaranteed, no spill risk.
__global__ __launch_bounds__(256, 2) void tbcnn_main_bf(
    const int* __restrict__ children, const ushort* __restrict__ embBf,
    const uint4* __restrict__ w1frag, const uint4* __restrict__ w2frag,
    const float* __restrict__ b1, const float* __restrict__ b2,
    unsigned* __restrict__ pooled, unsigned* __restrict__ done,
    float* __restrict__ out)
{
  __shared__ __align__(16) unsigned char wf_raw[2][TM * 768];   // 48 KB
  __shared__ unsigned last_flag;
  // XCD swizzle: 512 = 8 XCDs x 64; XCD x owns batches 4x..4x+3
  const int j0 = ((blockIdx.x & 7) << 6) | (blockIdx.x >> 3);
  const int b = j0 >> 4;
  const int tile0 = (j0 & 15) * TPB;
  const int t = threadIdx.x;
  const int lane = t & 63;
  const int w = t >> 6;
  const int nloc = t >> 3;
  const int q = t & 7;
  const int d0 = q * 16;
  const size_t rowbase = (size_t)b * NN;

  // ---- prologue: full pipelined gather of tile0 -> buf0 (R8 structure) ----
  {
    const int gn = tile0 * TM + nloc;
    const int4* chp4 = (const int4*)(children + (rowbase + gn) * NC);
    const int4 vA = chp4[0], vB = chp4[1], vC = chp4[2], vD = chp4[3];
    int ns = (vA.x > 0) + (vA.y > 0) + (vA.z > 0) + (vA.w > 0)
           + (vB.x > 0) + (vB.y > 0) + (vB.z > 0) + (vB.w > 0)
           + (vC.x > 0) + (vC.y > 0) + (vC.z > 0) + (vC.w > 0)
           + (vD.x > 0) + (vD.y > 0) + (vD.z > 0) + (vD.w > 0);
    const float rdiv = 1.0f / (float)(((ns - 1) > 1) ? (ns - 1) : 1);
    const bool one_sib = (ns == 1);
    const ushort* sp = embBf + (rowbase + gn) * ND + d0;
    stq(wf_raw[0], 768, nloc, 2 * d0,       *(const uint4*)sp);
    stq(wf_raw[0], 768, nloc, 2 * (d0 + 8), *(const uint4*)(sp + 8));

    f32x2 aR2[8], aL2[8];
    #pragma unroll
    for (int i = 0; i < 8; ++i){ aR2[i] = (f32x2){0.f,0.f}; aL2[i] = (f32x2){0.f,0.f}; }
    uint4 s0[4], t0[4], s1[4];
    ISSUE_LO(vA, s0)
    ISSUE_HI(vA, s1)
    ISSUE_LO(vB, t0)
    __builtin_amdgcn_sched_barrier(0);
    PROC_LO(0, vA, s0)
    PROC_HI(0, vA, s1)
    ISSUE_HI(vB, s1)
    ISSUE_LO(vC, s0)
    __builtin_amdgcn_sched_barrier(0);
    PROC_LO(1, vB, t0)
    PROC_HI(1, vB, s1)
    ISSUE_HI(vC, s1)
    ISSUE_LO(vD, t0)
    __builtin_amdgcn_sched_barrier(0);
    PROC_LO(2, vC, s0)
    PROC_HI(2, vC, s1)
    ISSUE_HI(vD, s1)
    __builtin_amdgcn_sched_barrier(0);
    PROC_LO(3, vD, t0)
    PROC_HI(3, vD, s1)
    STORE_ACC(wf_raw[0])
  }
  __syncthreads();

  // ---- 4-tile loop: MFMA(cur) interleaved with gather(next) ----
  #pragma unroll
  for (int it = 0; it < TPB; ++it){
    unsigned char* bufc = wf_raw[it & 1];
    unsigned char* bufn = wf_raw[(it & 1) ^ 1];
    f32x4 acc00 = (f32x4){0.f,0.f,0.f,0.f}, acc01 = (f32x4){0.f,0.f,0.f,0.f};
    f32x4 acc10 = (f32x4){0.f,0.f,0.f,0.f}, acc11 = (f32x4){0.f,0.f,0.f,0.f};

    if (it < TPB - 1){
      const int gn = (tile0 + it + 1) * TM + nloc;
      const int4* chp4 = (const int4*)(children + (rowbase + gn) * NC);
      const int4 vA = chp4[0], vB = chp4[1], vC = chp4[2], vD = chp4[3];
      int ns = (vA.x > 0) + (vA.y > 0) + (vA.z > 0) + (vA.w > 0)
             + (vB.x > 0) + (vB.y > 0) + (vB.z > 0) + (vB.w > 0)
             + (vC.x > 0) + (vC.y > 0) + (vC.z > 0) + (vC.w > 0)
             + (vD.x > 0) + (vD.y > 0) + (vD.z > 0) + (vD.w > 0);
      const float rdiv = 1.0f / (float)(((ns - 1) > 1) ? (ns - 1) : 1);
      const bool one_sib = (ns == 1);
      const ushort* sp = embBf + (rowbase + gn) * ND + d0;

      f32x2 aR2[8], aL2[8];
      #pragma unroll
      for (int i = 0; i < 8; ++i){ aR2[i] = (f32x2){0.f,0.f}; aL2[i] = (f32x2){0.f,0.f}; }
      uint4 sA0[4], sA1[4];

      // P0: issue self + group A
      uint4 selfL = *(const uint4*)sp;
      uint4 selfH = *(const uint4*)(sp + 8);
      ISSUE_LO(vA, sA0) ISSUE_HI(vA, sA1)
      __builtin_amdgcn_sched_barrier(0);
      // P1: MFMA ks 0..3 (hides A latency)
      MFMA_STEP(0) MFMA_STEP(1) MFMA_STEP(2) MFMA_STEP(3)
      __builtin_amdgcn_sched_barrier(0);
      // P2: process A, issue B
      PROC_LO(0, vA, sA0) PROC_HI(0, vA, sA1)
      ISSUE_LO(vB, sA0) ISSUE_HI(vB, sA1)
      __builtin_amdgcn_sched_barrier(0);
      // P3: MFMA ks 4..7
      MFMA_STEP(4) MFMA_STEP(5) MFMA_STEP(6) MFMA_STEP(7)
      __builtin_amdgcn_sched_barrier(0);
      // P4: process B, issue C
      PROC_LO(1, vB, sA0) PROC_HI(1, vB, sA1)
      ISSUE_LO(vC, sA0) ISSUE_HI(vC, sA1)
      __builtin_amdgcn_sched_barrier(0);
      // P5: MFMA ks 8..11
      MFMA_STEP(8) MFMA_STEP(9) MFMA_STEP(10) MFMA_STEP(11)
      __builtin_amdgcn_sched_barrier(0);
      // P6: process C, issue D, stash self
      PROC_LO(2, vC, sA0) PROC_HI(2, vC, sA1)
      ISSUE_LO(vD, sA0) ISSUE_HI(vD, sA1)
      stq(bufn, 768, nloc, 2 * d0,       selfL);
      stq(bufn, 768, nloc, 2 * (d0 + 8), selfH);
      __builtin_amdgcn_sched_barrier(0);
      // P7: epilogue of cur tile (hides D latency)
      EPI_MAXATOMIC
      __builtin_amdgcn_sched_barrier(0);
      // P8: process D, store accumulators
      PROC_LO(3, vD, sA0) PROC_HI(3, vD, sA1)
      STORE_ACC(bufn)
    } else {
      MFMA_STEP(0) MFMA_STEP(1) MFMA_STEP(2)  MFMA_STEP(3)
      MFMA_STEP(4) MFMA_STEP(5) MFMA_STEP(6)  MFMA_STEP(7)
      MFMA_STEP(8) MFMA_STEP(9) MFMA_STEP(10) MFMA_STEP(11)
      EPI_MAXATOMIC
    }
    __syncthreads();
  }

  // ---- last-block ticket (no fence; atomics device-coherent — R5 lesson) ----
  if (t == 0){
    unsigned r = atomicAdd(done, 1u);
    last_flag = (r == NBLK2 - 1) ? 1u : 0u;
  }
  __syncthreads();
  if (!last_flag) return;

  FUSED_FINAL(wf_raw[0])
}

// ---- f32 fallback (ws too small for embBf): R6 structure, 2048 blocks ----
__global__ __launch_bounds__(256, 2) void tbcnn_main_f32(
    const int* __restrict__ children, const float* __restrict__ nodeEmb,
    const uint4* __restrict__ w1frag, const uint4* __restrict__ w2frag,
    const float* __restrict__ b1, const float* __restrict__ b2,
    unsigned* __restrict__ pooled, unsigned* __restrict__ done,
    float* __restrict__ out)
{
  __shared__ __align__(16) unsigned char wf_raw[TM * 768];
  __shared__ unsigned last_flag;
  const int j0 = ((blockIdx.x & 7) << 8) | (blockIdx.x >> 3);
  const int b = j0 >> 6;
  const int n0 = (j0 & 63) * TM;
  const int t = threadIdx.x;
  const int lane = t & 63;
  const int w = t >> 6;
  {
    const int nloc = t >> 3;
    const int q = t & 7;
    const int d0 = q * 16;
    const int gn = n0 + nloc;
    const int4* chp4 = (const int4*)(children + ((size_t)b * NN + gn) * NC);
    int ns = 0;
    #pragma unroll
    for (int c4 = 0; c4 < 4; ++c4){
      int4 v = chp4[c4];
      ns += (v.x > 0) + (v.y > 0) + (v.z > 0) + (v.w > 0);
    }
    const float rdiv = 1.0f / (float)(((ns - 1) > 1) ? (ns - 1) : 1);
    const bool one_sib = (ns == 1);
    const size_t rowbase = (size_t)b * NN;
    const float* sp = nodeEmb + (rowbase + gn) * ND + d0;
    float sv[16];
    #pragma unroll
    for (int j = 0; j < 4; ++j){
      float4 s = *(const float4*)(sp + j * 4);
      sv[j*4+0]=s.x; sv[j*4+1]=s.y; sv[j*4+2]=s.z; sv[j*4+3]=s.w;
    }
    st8(wf_raw, 768, nloc, 2 * d0, sv);
    st8(wf_raw, 768, nloc, 2 * (d0 + 8), sv + 8);
    float aR[16], aL[16];
    #pragma unroll
    for (int i = 0; i < 16; ++i){ aR[i] = 0.0f; aL[i] = 0.0f; }
    #pragma unroll
    for (int c4 = 0; c4 < 4; ++c4){
      int4 v = chp4[c4];
      int cidx[4] = {v.x, v.y, v.z, v.w};
      #pragma unroll
      for (int jj = 0; jj < 4; ++jj){
        const int c = c4 * 4 + jj;
        const int idx = cidx[jj];
        const float mk  = (idx > 0) ? 1.0f : 0.0f;
        const float wrc = one_sib ? (0.5f * mk) : (mk * (float)c * rdiv);
        const float wlc = (1.0f - wrc) * mk;
        const float* cp = nodeEmb + (rowbase + idx) * ND + d0;
        #pragma unroll
        for (int j = 0; j < 4; ++j){
          float4 u = *(const float4*)(cp + j * 4);
          aR[j*4+0] += wrc * u.x; aL[j*4+0] += wlc * u.x;
          aR[j*4+1] += wrc * u.y; aL[j*4+1] += wlc * u.y;
          aR[j*4+2] += wrc * u.z; aL[j*4+2] += wlc * u.z;
          aR[j*4+3] += wrc * u.w; aL[j*4+3] += wlc * u.w;
        }
      }
    }
    st8(wf_raw, 768, nloc, 2 * (ND + d0),         aR);
    st8(wf_raw, 768, nloc, 2 * (ND + d0 + 8),     aR + 8);
    st8(wf_raw, 768, nloc, 2 * (2 * ND + d0),     aL);
    st8(wf_raw, 768, nloc, 2 * (2 * ND + d0 + 8), aL + 8);
  }
  __syncthreads();
  {
    unsigned char* bufc = wf_raw;
    f32x4 acc00 = (f32x4){0.f,0.f,0.f,0.f}, acc01 = (f32x4){0.f,0.f,0.f,0.f};
    f32x4 acc10 = (f32x4){0.f,0.f,0.f,0.f}, acc11 = (f32x4){0.f,0.f,0.f,0.f};
    #pragma unroll 4
    for (int ks = 0; ks < 12; ++ks){
      MFMA_STEP(ks)
    }
    EPI_MAXATOMIC
  }
  __syncthreads();
  if (t == 0){
    unsigned r = atomicAdd(done, 1u);
    last_flag = (r == NBLKF - 1) ? 1u : 0u;
  }
  __syncthreads();
  if (!last_flag) return;
  FUSED_FINAL(wf_raw)
}

extern "C" void kernel_launch(void* const* d_in, const int* in_sizes, int n_in,
                              void* d_out, int out_size, void* d_ws, size_t ws_size,
                              hipStream_t stream)
{
  const int*   children = (const int*)d_in[0];
  const float* nodeEmb  = (const float*)d_in[1];
  const float* W1       = (const float*)d_in[2];
  const float* b1       = (const float*)d_in[3];
  const float* W2       = (const float*)d_in[4];
  const float* b2       = (const float*)d_in[5];
  float* out = (float*)d_out;

  unsigned* pooled = (unsigned*)((char*)d_ws + OFF_POOLED);
  uint4* w1frag    = (uint4*)((char*)d_ws + OFF_W1);
  uint4* w2frag    = (uint4*)((char*)d_ws + OFF_W2);
  unsigned* done   = (unsigned*)((char*)d_ws + OFF_DONE);
  ushort* embBf    = (ushort*)((char*)d_ws + OFF_EMB);

  const bool bf = (ws_size >= WS_NEED_BF);

  tbcnn_prep<<<2080, 256, 0, stream>>>(nodeEmb, W1, W2, pooled, w1frag, w2frag, embBf, done, bf ? 1 : 0);
  if (bf)
    tbcnn_main_bf<<<NBLK2, 256, 0, stream>>>(children, embBf, w1frag, w2frag, b1, b2, pooled, done, out);
  else
    tbcnn_main_f32<<<NBLKF, 256, 0, stream>>>(children, nodeEmb, w1frag, w2frag, b1, b2, pooled, done, out);
}

// Round 10
// 45.593 us; speedup vs baseline: 1.2926x; 1.1397x over previous
//
#include <hip/hip_runtime.h>

#define NB 32
#define NN 2048
#define NC 16
#define ND 128
#define NH 128
#define TM 32
#define NBLK (NB * (NN / TM))   // 2048 blocks of 256 threads

typedef __bf16 bf16x8 __attribute__((ext_vector_type(8)));
typedef float f32x4 __attribute__((ext_vector_type(4)));
typedef float f32x2 __attribute__((ext_vector_type(2)));

__device__ __forceinline__ unsigned short f2bf(float f){
  unsigned u = __float_as_uint(f);
  u = (u + 0x7fffu + ((u >> 16) & 1u)) >> 16;   // RNE
  return (unsigned short)u;
}
__device__ __forceinline__ unsigned enc_f32(float x){
  unsigned u = __float_as_uint(x);
  return (u & 0x80000000u) ? ~u : (u | 0x80000000u);
}
__device__ __forceinline__ float dec_f32(unsigned u){
  return __uint_as_float((u & 0x80000000u) ? (u & 0x7fffffffu) : ~u);
}

// swizzled LDS tile helpers (XOR bank swizzle: byte ^= (row&7)<<4)
__device__ __forceinline__ void stq(unsigned char* base, int stride, int row, int koff, uint4 u){
  *(uint4*)(base + row * stride + (koff ^ ((row & 7) << 4))) = u;
}
__device__ __forceinline__ void st8(unsigned char* base, int stride, int row, int koff, const float* f){
  uint4 u;
  u.x = (unsigned)f2bf(f[0]) | ((unsigned)f2bf(f[1]) << 16);
  u.y = (unsigned)f2bf(f[2]) | ((unsigned)f2bf(f[3]) << 16);
  u.z = (unsigned)f2bf(f[4]) | ((unsigned)f2bf(f[5]) << 16);
  u.w = (unsigned)f2bf(f[6]) | ((unsigned)f2bf(f[7]) << 16);
  stq(base, stride, row, koff, u);
}
__device__ __forceinline__ void st8p(unsigned char* base, int stride, int row, int koff, const f32x2* p){
  uint4 u;
  u.x = (unsigned)f2bf(p[0][0]) | ((unsigned)f2bf(p[0][1]) << 16);
  u.y = (unsigned)f2bf(p[1][0]) | ((unsigned)f2bf(p[1][1]) << 16);
  u.z = (unsigned)f2bf(p[2][0]) | ((unsigned)f2bf(p[2][1]) << 16);
  u.w = (unsigned)f2bf(p[3][0]) | ((unsigned)f2bf(p[3][1]) << 16);
  stq(base, stride, row, koff, u);
}
__device__ __forceinline__ uint4 ldq(const unsigned char* base, int stride, int row, int koff){
  return *(const uint4*)(base + row * stride + (koff ^ ((row & 7) << 4)));
}

// ws layout (no ticket flag anymore)
#define OFF_POOLED 0
#define OFF_W1     16384
#define OFF_W2     114688
#define OFF_EMB    147456
#define WS_NEED_BF (OFF_EMB + (size_t)NB*NN*ND*2)

// ---- unified prep ----
// blocks [0,2048): nodeEmb f32 -> bf16, XCD-affine (chunk for batch b on b's XCD)
// blocks [2048,2072): W1 frags [cf][ks][lane]x16B ; pooled init
// blocks [2072,2080): W2 frags [cf][ks][lane]x16B
__global__ __launch_bounds__(256) void tbcnn_prep(
    const float* __restrict__ nodeEmb, const float* __restrict__ W1,
    const float* __restrict__ W2, unsigned* __restrict__ pooled,
    uint4* __restrict__ w1frag, uint4* __restrict__ w2frag,
    ushort* __restrict__ embBf, int doEmb)
{
  const int blk = blockIdx.x;
  const int t = threadIdx.x;
  if (blk < 2048){
    if (!doEmb) return;
    const int chk = ((blk & 7) << 8) | (blk >> 3);
    const float4* src = (const float4*)nodeEmb;
    #pragma unroll
    for (int it = 0; it < 4; ++it){
      const int i = chk * 1024 + it * 256 + t;
      float4 v = src[i];
      ushort4 o;
      o.x = f2bf(v.x); o.y = f2bf(v.y); o.z = f2bf(v.z); o.w = f2bf(v.w);
      *(ushort4*)(embBf + (size_t)i * 4) = o;
    }
  } else if (blk < 2072){
    const int tt = (blk - 2048) * 256 + t;        // 0..6143
    if (tt < NB * NH) pooled[tt] = 0u;            // enc-min (any real value wins)
    const int lane = tt & 63;
    const int rest = tt >> 6;                     // 0..95
    const int ks = rest % 12;
    const int cf = rest / 12;
    const int col = (cf >> 1) * 32 + (cf & 1) * 16 + (lane & 15);
    const int k0 = ks * 32 + (lane >> 4) * 8;
    unsigned ps[4];
    #pragma unroll
    for (int p = 0; p < 4; ++p){
      unsigned lo = f2bf(W1[(size_t)(k0 + 2*p) * NH + col]);
      unsigned hi = f2bf(W1[(size_t)(k0 + 2*p + 1) * NH + col]);
      ps[p] = lo | (hi << 16);
    }
    w1frag[tt] = make_uint4(ps[0], ps[1], ps[2], ps[3]);
  } else {
    const int tt = (blk - 2072) * 256 + t;        // 0..2047
    const int lane = tt & 63;
    const int rest = tt >> 6;
    const int ks = rest & 3;
    const int cf = rest >> 2;
    const int col = (cf >> 1) * 32 + (cf & 1) * 16 + (lane & 15);
    const int k0 = ks * 32 + (lane >> 4) * 8;
    unsigned ps[4];
    #pragma unroll
    for (int p = 0; p < 4; ++p){
      unsigned lo = f2bf(W2[(size_t)(k0 + 2*p) * NH + col]);
      unsigned hi = f2bf(W2[(size_t)(k0 + 2*p + 1) * NH + col]);
      ps[p] = lo | (hi << 16);
    }
    w2frag[tt] = make_uint4(ps[0], ps[1], ps[2], ps[3]);
  }
}

#define PROC2(u, p) { \
  f32x2 x_; \
  x_[0] = __uint_as_float((u) << 16); \
  x_[1] = __uint_as_float((u) & 0xffff0000u); \
  aR2[(p)] += w_r * x_; \
  aL2[(p)] += w_l * x_; }

#define ISSUE_LO(vv, D) { \
  D[0] = *(const uint4*)(embBf + (rowbase + (vv).x) * ND + d0); \
  D[1] = *(const uint4*)(embBf + (rowbase + (vv).y) * ND + d0); \
  D[2] = *(const uint4*)(embBf + (rowbase + (vv).z) * ND + d0); \
  D[3] = *(const uint4*)(embBf + (rowbase + (vv).w) * ND + d0); }
#define ISSUE_HI(vv, D) { \
  D[0] = *(const uint4*)(embBf + (rowbase + (vv).x) * ND + d0 + 8); \
  D[1] = *(const uint4*)(embBf + (rowbase + (vv).y) * ND + d0 + 8); \
  D[2] = *(const uint4*)(embBf + (rowbase + (vv).z) * ND + d0 + 8); \
  D[3] = *(const uint4*)(embBf + (rowbase + (vv).w) * ND + d0 + 8); }

#define CW(c, idx) \
  const float mk  = ((idx) > 0) ? 1.0f : 0.0f; \
  const float wrc = one_sib ? (0.5f * mk) : (mk * (float)(c) * rdiv); \
  const float wlc = (1.0f - wrc) * mk; \
  const f32x2 w_r = (f32x2){wrc, wrc}; \
  const f32x2 w_l = (f32x2){wlc, wlc};

#define PROC_LO(g, vv, U) { \
  { CW(4*(g)+0, (vv).x) PROC2(U[0].x, 0) PROC2(U[0].y, 1) PROC2(U[0].z, 2) PROC2(U[0].w, 3) } \
  { CW(4*(g)+1, (vv).y) PROC2(U[1].x, 0) PROC2(U[1].y, 1) PROC2(U[1].z, 2) PROC2(U[1].w, 3) } \
  { CW(4*(g)+2, (vv).z) PROC2(U[2].x, 0) PROC2(U[2].y, 1) PROC2(U[2].z, 2) PROC2(U[2].w, 3) } \
  { CW(4*(g)+3, (vv).w) PROC2(U[3].x, 0) PROC2(U[3].y, 1) PROC2(U[3].z, 2) PROC2(U[3].w, 3) } }
#define PROC_HI(g, vv, U) { \
  { CW(4*(g)+0, (vv).x) PROC2(U[0].x, 4) PROC2(U[0].y, 5) PROC2(U[0].z, 6) PROC2(U[0].w, 7) } \
  { CW(4*(g)+1, (vv).y) PROC2(U[1].x, 4) PROC2(U[1].y, 5) PROC2(U[1].z, 6) PROC2(U[1].w, 7) } \
  { CW(4*(g)+2, (vv).z) PROC2(U[2].x, 4) PROC2(U[2].y, 5) PROC2(U[2].z, 6) PROC2(U[2].w, 7) } \
  { CW(4*(g)+3, (vv).w) PROC2(U[3].x, 4) PROC2(U[3].y, 5) PROC2(U[3].z, 6) PROC2(U[3].w, 7) } }

// ---- main: gather (sched_barrier pipelined, R8) + wf (LDS) + MFMA + atomicMax.
// NO exit ticket / fused final (R9 post-mortem: atomicAdd(done)+tail cost ~7-10us).
// (256,2): 256-VGPR cap; never force occupancy (R2/R4: <64 VGPR -> 300MB spill).
// No __threadfence (R5: device fence demoted L2 gather set).
template<bool BF>
__global__ __launch_bounds__(256, 2) void tbcnn_main(
    const int* __restrict__ children, const float* __restrict__ nodeEmb,
    const ushort* __restrict__ embBf, const uint4* __restrict__ w1frag,
    unsigned* __restrict__ pooled)
{
  __shared__ __align__(16) unsigned char wf_raw[TM * 768];   // 24 KB
  // XCD-aware swizzle: 2048 blocks = 8 XCDs x 256; each XCD owns 4 batches
  const int j0 = ((blockIdx.x & 7) << 8) | (blockIdx.x >> 3);
  const int b = j0 >> 6;
  const int n0 = (j0 & 63) * TM;
  const int t = threadIdx.x;
  const int lane = t & 63;
  const int w = t >> 6;

  // ---- gather phase: 8 threads per node, 16 dims each ----
  {
    const int nloc = t >> 3;
    const int q = t & 7;
    const int d0 = q * 16;
    const int gn = n0 + nloc;
    const int4* chp4 = (const int4*)(children + ((size_t)b * NN + gn) * NC);
    const size_t rowbase = (size_t)b * NN;

    const int4 vA = chp4[0], vB = chp4[1], vC = chp4[2], vD = chp4[3];
    int ns = (vA.x > 0) + (vA.y > 0) + (vA.z > 0) + (vA.w > 0)
           + (vB.x > 0) + (vB.y > 0) + (vB.z > 0) + (vB.w > 0)
           + (vC.x > 0) + (vC.y > 0) + (vC.z > 0) + (vC.w > 0)
           + (vD.x > 0) + (vD.y > 0) + (vD.z > 0) + (vD.w > 0);
    const float rdiv = 1.0f / (float)(((ns - 1) > 1) ? (ns - 1) : 1);
    const bool one_sib = (ns == 1);

    if (BF){
      // self -> k-block 0
      const ushort* sp = embBf + (rowbase + gn) * ND + d0;
      stq(wf_raw, 768, nloc, 2 * d0,       *(const uint4*)sp);
      stq(wf_raw, 768, nloc, 2 * (d0 + 8), *(const uint4*)(sp + 8));

      // children weighted sums, software-pipelined:
      // round g: issue {hi of g, lo of g+1} (8 loads in flight), fence, process g.
      f32x2 aR2[8], aL2[8];
      #pragma unroll
      for (int i = 0; i < 8; ++i){ aR2[i] = (f32x2){0.f,0.f}; aL2[i] = (f32x2){0.f,0.f}; }

      uint4 s0[4], t0[4], s1[4];           // named buffers, static indexing only
      ISSUE_LO(vA, s0)
      ISSUE_HI(vA, s1)
      ISSUE_LO(vB, t0)
      __builtin_amdgcn_sched_barrier(0);
      PROC_LO(0, vA, s0)
      PROC_HI(0, vA, s1)
      ISSUE_HI(vB, s1)
      ISSUE_LO(vC, s0)
      __builtin_amdgcn_sched_barrier(0);
      PROC_LO(1, vB, t0)
      PROC_HI(1, vB, s1)
      ISSUE_HI(vC, s1)
      ISSUE_LO(vD, t0)
      __builtin_amdgcn_sched_barrier(0);
      PROC_LO(2, vC, s0)
      PROC_HI(2, vC, s1)
      ISSUE_HI(vD, s1)
      __builtin_amdgcn_sched_barrier(0);
      PROC_LO(3, vD, t0)
      PROC_HI(3, vD, s1)

      st8p(wf_raw, 768, nloc, 2 * (ND + d0),         aR2);
      st8p(wf_raw, 768, nloc, 2 * (ND + d0 + 8),     aR2 + 4);
      st8p(wf_raw, 768, nloc, 2 * (2 * ND + d0),     aL2);
      st8p(wf_raw, 768, nloc, 2 * (2 * ND + d0 + 8), aL2 + 4);
    } else {
      const float* sp = nodeEmb + (rowbase + gn) * ND + d0;
      float sv[16];
      #pragma unroll
      for (int j = 0; j < 4; ++j){
        float4 s = *(const float4*)(sp + j * 4);
        sv[j*4+0]=s.x; sv[j*4+1]=s.y; sv[j*4+2]=s.z; sv[j*4+3]=s.w;
      }
      st8(wf_raw, 768, nloc, 2 * d0, sv);
      st8(wf_raw, 768, nloc, 2 * (d0 + 8), sv + 8);
      float aR[16], aL[16];
      #pragma unroll
      for (int i = 0; i < 16; ++i){ aR[i] = 0.0f; aL[i] = 0.0f; }
      const int4 vs[4] = {vA, vB, vC, vD};
      #pragma unroll
      for (int c4 = 0; c4 < 4; ++c4){
        int cidx[4] = {vs[c4].x, vs[c4].y, vs[c4].z, vs[c4].w};
        #pragma unroll
        for (int jj = 0; jj < 4; ++jj){
          const int c = c4 * 4 + jj;
          const int idx = cidx[jj];
          const float mk  = (idx > 0) ? 1.0f : 0.0f;
          const float wrc = one_sib ? (0.5f * mk) : (mk * (float)c * rdiv);
          const float wlc = (1.0f - wrc) * mk;
          const float* cp = nodeEmb + (rowbase + idx) * ND + d0;
          #pragma unroll
          for (int j = 0; j < 4; ++j){
            float4 u = *(const float4*)(cp + j * 4);
            aR[j*4+0] += wrc * u.x; aL[j*4+0] += wlc * u.x;
            aR[j*4+1] += wrc * u.y; aL[j*4+1] += wlc * u.y;
            aR[j*4+2] += wrc * u.z; aL[j*4+2] += wlc * u.z;
            aR[j*4+3] += wrc * u.w; aL[j*4+3] += wlc * u.w;
          }
        }
      }
      st8(wf_raw, 768, nloc, 2 * (ND + d0),         aR);
      st8(wf_raw, 768, nloc, 2 * (ND + d0 + 8),     aR + 8);
      st8(wf_raw, 768, nloc, 2 * (2 * ND + d0),     aL);
      st8(wf_raw, 768, nloc, 2 * (2 * ND + d0 + 8), aL + 8);
    }
  }
  __syncthreads();

  // ---- MFMA: 32 rows x 32 cols per wave, K=384; B frags streamed (L2-hot) ----
  {
    f32x4 acc[2][2];
    #pragma unroll
    for (int rf = 0; rf < 2; ++rf){
      acc[rf][0] = (f32x4){0.f, 0.f, 0.f, 0.f};
      acc[rf][1] = (f32x4){0.f, 0.f, 0.f, 0.f};
    }
    #pragma unroll 4
    for (int ks = 0; ks < 12; ++ks){
      bf16x8 B0 = __builtin_bit_cast(bf16x8, w1frag[((w * 2 + 0) * 12 + ks) * 64 + lane]);
      bf16x8 B1 = __builtin_bit_cast(bf16x8, w1frag[((w * 2 + 1) * 12 + ks) * 64 + lane]);
      const int koff = ks * 64 + ((lane >> 4) << 4);
      #pragma unroll
      for (int rf = 0; rf < 2; ++rf){
        const int row = rf * 16 + (lane & 15);
        bf16x8 a = __builtin_bit_cast(bf16x8, ldq(wf_raw, 768, row, koff));
        acc[rf][0] = __builtin_amdgcn_mfma_f32_16x16x32_bf16(a, B0, acc[rf][0], 0, 0, 0);
        acc[rf][1] = __builtin_amdgcn_mfma_f32_16x16x32_bf16(a, B1, acc[rf][1], 0, 0, 0);
      }
    }

    float m0 = -3.0e38f, m1 = -3.0e38f;
    #pragma unroll
    for (int rf = 0; rf < 2; ++rf)
      #pragma unroll
      for (int i = 0; i < 4; ++i){
        m0 = fmaxf(m0, acc[rf][0][i]);
        m1 = fmaxf(m1, acc[rf][1][i]);
      }
    m0 = fmaxf(m0, __shfl_xor(m0, 16, 64));
    m0 = fmaxf(m0, __shfl_xor(m0, 32, 64));
    m1 = fmaxf(m1, __shfl_xor(m1, 16, 64));
    m1 = fmaxf(m1, __shfl_xor(m1, 32, 64));
    if (lane < 16){
      atomicMax(pooled + b * NH + w * 32 + lane,      enc_f32(m0));
      atomicMax(pooled + b * NH + w * 32 + 16 + lane, enc_f32(m1));
    }
  }
}

// ---- final: h=tanh(pooled+b1) -> MFMA h@W2 -> tanh -> cosine(v1,v2) ----
// separate kernel: stream order guarantees visibility of main's atomics.
__global__ __launch_bounds__(256) void tbcnn_final(
    const unsigned* __restrict__ pooled, const float* __restrict__ b1,
    const uint4* __restrict__ w2frag, const float* __restrict__ b2,
    float* __restrict__ out)
{
  __shared__ __align__(16) unsigned char hls[NB * 256];   // 32 x 128 bf16, swizzled
  __shared__ float os[NB * NH];
  const int t = threadIdx.x;
  const int lane = t & 63;
  const int w = t >> 6;

  {
    const int row = t >> 3;          // batch
    const int q = t & 7;
    const int d0 = q * 16;
    const unsigned* pp = pooled + row * NH + d0;
    const float* bp = b1 + d0;
    float hv[16];
    #pragma unroll
    for (int j = 0; j < 16; ++j) hv[j] = tanhf(dec_f32(pp[j]) + bp[j]);
    st8(hls, 256, row, 2 * d0, hv);
    st8(hls, 256, row, 2 * (d0 + 8), hv + 8);
  }
  __syncthreads();
  {
    f32x4 acc[2][2];
    #pragma unroll
    for (int rf = 0; rf < 2; ++rf){
      acc[rf][0] = (f32x4){0.f,0.f,0.f,0.f};
      acc[rf][1] = (f32x4){0.f,0.f,0.f,0.f};
    }
    #pragma unroll
    for (int ks = 0; ks < 4; ++ks){
      bf16x8 B0 = __builtin_bit_cast(bf16x8, w2frag[((w * 2 + 0) * 4 + ks) * 64 + lane]);
      bf16x8 B1 = __builtin_bit_cast(bf16x8, w2frag[((w * 2 + 1) * 4 + ks) * 64 + lane]);
      const int koff = ks * 64 + ((lane >> 4) << 4);
      #pragma unroll
      for (int rf = 0; rf < 2; ++rf){
        bf16x8 a = __builtin_bit_cast(bf16x8, ldq(hls, 256, rf * 16 + (lane & 15), koff));
        acc[rf][0] = __builtin_amdgcn_mfma_f32_16x16x32_bf16(a, B0, acc[rf][0], 0, 0, 0);
        acc[rf][1] = __builtin_amdgcn_mfma_f32_16x16x32_bf16(a, B1, acc[rf][1], 0, 0, 0);
      }
    }
    #pragma unroll
    for (int rf = 0; rf < 2; ++rf)
      #pragma unroll
      for (int cf = 0; cf < 2; ++cf){
        const int col = w * 32 + cf * 16 + (lane & 15);
        const float bias = b2[col];
        #pragma unroll
        for (int i = 0; i < 4; ++i){
          const int r = rf * 16 + (lane >> 4) * 4 + i;
          os[r * NH + col] = tanhf(acc[rf][cf][i] + bias);
        }
      }
  }
  __syncthreads();
  if (t < 16){
    float s12 = 0.f, s11 = 0.f, s22 = 0.f;
    #pragma unroll 4
    for (int d = 0; d < NH; ++d){
      float a = os[t * NH + d];
      float c = os[(t + 16) * NH + d];
      s12 += a * c; s11 += a * a; s22 += c * c;
    }
    float n1 = fmaxf(sqrtf(s11), 1e-8f);
    float n2 = fmaxf(sqrtf(s22), 1e-8f);
    out[t] = s12 / (n1 * n2);
  }
}

extern "C" void kernel_launch(void* const* d_in, const int* in_sizes, int n_in,
                              void* d_out, int out_size, void* d_ws, size_t ws_size,
                              hipStream_t stream)
{
  const int*   children = (const int*)d_in[0];
  const float* nodeEmb  = (const float*)d_in[1];
  const float* W1       = (const float*)d_in[2];
  const float* b1       = (const float*)d_in[3];
  const float* W2       = (const float*)d_in[4];
  const float* b2       = (const float*)d_in[5];
  float* out = (float*)d_out;

  unsigned* pooled = (unsigned*)((char*)d_ws + OFF_POOLED);
  uint4* w1frag    = (uint4*)((char*)d_ws + OFF_W1);
  uint4* w2frag    = (uint4*)((char*)d_ws + OFF_W2);
  ushort* embBf    = (ushort*)((char*)d_ws + OFF_EMB);

  const bool bf = (ws_size >= WS_NEED_BF);

  tbcnn_prep<<<2080, 256, 0, stream>>>(nodeEmb, W1, W2, pooled, w1frag, w2frag, embBf, bf ? 1 : 0);
  if (bf)
    tbcnn_main<true><<<NBLK, 256, 0, stream>>>(children, nodeEmb, embBf, w1frag, pooled);
  else
    tbcnn_main<false><<<NBLK, 256, 0, stream>>>(children, nodeEmb, embBf, w1frag, pooled);
  tbcnn_final<<<1, 256, 0, stream>>>(pooled, b1, w2frag, b2, out);
}